// Round 1
// 58.990 us; speedup vs baseline: 1.0256x; 1.0256x over previous
//
#include <hip/hip_runtime.h>

#define PI_F 3.14159265358979323846f
#define INV_SQRT2 0.70710678118654752440f
#define INV_2PI 0.15915494309189535f

// Hardware sincos: v_sin_f32/v_cos_f32 take revolutions (D = sin(S0*2pi)).
// fract() gives exact period reduction, so this is valid for any finite x;
// precision ~1e-6 abs, far under the output tolerance (prev absmax = 0.0).
__device__ __forceinline__ void hw_sincos(float x, float* s, float* c) {
    const float r = x * INV_2PI;
    const float f = r - floorf(r);          // v_fract
    *s = __builtin_amdgcn_sinf(f);
    *c = __builtin_amdgcn_cosf(f);
}

// tanh via native exp: tanh(x) = (e^{2x}-1)/(e^{2x}+1). |x| <~ 6 here, no overflow.
__device__ __forceinline__ float fast_tanh(float x) {
    const float e = __expf(2.0f * x);       // v_exp_f32 path
    return __fdividef(e - 1.0f, e + 1.0f);
}

// Light-cone exact reduction: z(n,q) depends only on qubits (q-3..q+3) mod 16.
// Per (n,q): 7-qubit (128-amp) sim with the surviving gates:
//   product init -> 6x CRZ(i,i+1) [D0 window] -> RY(alpha) on {q-2,q,q+2}
//   -> 2x CRZ {(q-2,q),(q,q+2)} [D1 window] -> RY(beta_q) on q -> <Z_q>.
// One wave per (n,q): 64 lanes x 2 amps (local qubit 6 = register bit).
__global__ __launch_bounds__(256)
void lightcone_qsim(const float* __restrict__ x, const float* __restrict__ wcrz,
                    const float* __restrict__ wry, const float* __restrict__ scale_p,
                    float* __restrict__ out) {
    const int tid = threadIdx.x, wid = tid >> 6, l = tid & 63;
    const int n = blockIdx.x >> 2;                 // circuit 0..63
    const int q = ((blockIdx.x & 3) << 2) | wid;   // measured qubit 0..15

    __shared__ float v0[16], v1[16];       // init state per qubit: RY(enc)*H|0>
    __shared__ float ac[16], as_[16];      // alpha = wry0 + enc (half-angle c/s)
    __shared__ float bcx[16], bsx[16];     // beta = wry1
    __shared__ float t0[16], t1[16];       // CRZ half-angles, layers 0/1

    if (tid < 16) {
        const int qq = tid, b = n >> 3, p = n & 7, h = qq >> 2, w = qq & 3;
        const float enc = fast_tanh(x[b*128 + h*32 + p*4 + w] * scale_p[0]) * PI_F;
        float s, c; hw_sincos(0.5f * enc, &s, &c);
        v0[qq] = (c - s) * INV_SQRT2;
        v1[qq] = (c + s) * INV_SQRT2;
        hw_sincos(0.5f * (wry[qq] + enc), &as_[qq], &ac[qq]);   // merged RY(w0)+RY(enc)
        hw_sincos(0.5f * wry[16 + qq], &bsx[qq], &bcx[qq]);
        t0[qq] = 0.5f * wcrz[qq];
        t1[qq] = 0.5f * wcrz[16 + qq];
    }
    __syncthreads();

    // window qubits: local i -> global m[i] = q-3+i (mod 16); center = local 3
    int m[7];
#pragma unroll
    for (int i = 0; i < 7; ++i) m[i] = (q + 13 + i) & 15;

    int bit[6];
#pragma unroll
    for (int i = 0; i < 6; ++i) bit[i] = (l >> i) & 1;

    // product init (real); two amps per lane: local bit 6 = r in {0,1}
    float prod = 1.f;
#pragma unroll
    for (int i = 0; i < 6; ++i) prod *= bit[i] ? v1[m[i]] : v0[m[i]];
    const float prod0 = prod * v0[m[6]];
    const float prod1 = prod * v1[m[6]];

    // D0 window: CRZ(local i -> i+1), i=0..5. phase = b_i ? (b_{i+1} ? +t : -t) : 0
    float base = 0.f;
#pragma unroll
    for (int i = 0; i < 5; ++i)
        if (bit[i]) base += bit[i + 1] ? t0[m[i]] : -t0[m[i]];
    const float ang0 = base + (bit[5] ? -t0[m[5]] : 0.f);   // r=0 (b6=0)
    const float ang1 = base + (bit[5] ? +t0[m[5]] : 0.f);   // r=1 (b6=1)
    float s0, c0, s1, c1;
    hw_sincos(ang0, &s0, &c0);       // independent -> dual-issue / overlap
    hw_sincos(ang1, &s1, &c1);
    float2 a0 = make_float2(prod0 * c0, prod0 * s0);
    float2 a1 = make_float2(prod1 * c1, prod1 * s1);

    // RY(alpha) on local qubits 1,3,5 (= global q-2, q, q+2): lane-shuffle butterflies
#pragma unroll
    for (int t = 0; t < 3; ++t) {
        const int i = 1 + 2 * t, mask = 1 << i;
        const float c = ac[m[i]], s = as_[m[i]];
        const float sg = bit[i] ? s : -s;
        const float p0x = __shfl_xor(a0.x, mask, 64), p0y = __shfl_xor(a0.y, mask, 64);
        const float p1x = __shfl_xor(a1.x, mask, 64), p1y = __shfl_xor(a1.y, mask, 64);
        a0 = make_float2(c*a0.x + sg*p0x, c*a0.y + sg*p0y);
        a1 = make_float2(c*a1.x + sg*p1x, c*a1.y + sg*p1y);
    }

    // D1 window: CRZ(local 1 -> 3) and CRZ(local 3 -> 5); lane bits only
    float phi1 = 0.f;
    if (bit[1]) phi1 += bit[3] ? t1[m[1]] : -t1[m[1]];
    if (bit[3]) phi1 += bit[5] ? t1[m[3]] : -t1[m[3]];
    float sp, cp; hw_sincos(phi1, &sp, &cp);
    a0 = make_float2(a0.x*cp - a0.y*sp, a0.x*sp + a0.y*cp);
    a1 = make_float2(a1.x*cp - a1.y*sp, a1.x*sp + a1.y*cp);

    // RY(beta_q) on local 3
    {
        const int mask = 8;
        const float c = bcx[q], s = bsx[q];
        const float sg = bit[3] ? s : -s;
        const float p0x = __shfl_xor(a0.x, mask, 64), p0y = __shfl_xor(a0.y, mask, 64);
        const float p1x = __shfl_xor(a1.x, mask, 64), p1y = __shfl_xor(a1.y, mask, 64);
        a0 = make_float2(c*a0.x + sg*p0x, c*a0.y + sg*p0y);
        a1 = make_float2(c*a1.x + sg*p1x, c*a1.y + sg*p1y);
    }

    // <Z_center>: sum (1-2*b3) * |amp|^2 over all 128 amps
    float val = a0.x*a0.x + a0.y*a0.y + a1.x*a1.x + a1.y*a1.y;
    val = bit[3] ? -val : val;
#pragma unroll
    for (int off = 1; off < 64; off <<= 1) val += __shfl_xor(val, off, 64);

    if (l == 0) {
        const int b = n >> 3, p = n & 7, h = q >> 2, w = q & 3;
        out[b*128 + h*32 + p*4 + w] = fminf(1.f, fmaxf(-1.f, val));
    }
}

extern "C" void kernel_launch(void* const* d_in, const int* in_sizes, int n_in,
                              void* d_out, int out_size, void* d_ws, size_t ws_size,
                              hipStream_t stream) {
    const float* x     = (const float*)d_in[0];
    const float* wcrz  = (const float*)d_in[1];
    const float* wry   = (const float*)d_in[2];
    const float* scale = (const float*)d_in[3];
    float* out = (float*)d_out;

    lightcone_qsim<<<256, 256, 0, stream>>>(x, wcrz, wry, scale, out);
}